// Round 1
// baseline (834.942 us; speedup 1.0000x reference)
//
#include <hip/hip_runtime.h>
#include <hip/hip_bf16.h>
#include <math.h>

#define B_ 4
#define S_ 2048
#define H_ 768
#define M_ (B_*S_)                 // 8192 rows
#define MN ((size_t)M_*(size_t)H_) // 6291456
#define HH (H_*H_)                 // 589824

typedef __bf16 bf16_t;
typedef __bf16 bf16x8 __attribute__((ext_vector_type(8)));
typedef float  f32x4  __attribute__((ext_vector_type(4)));

typedef __attribute__((address_space(3))) void       lds_void_t;
typedef __attribute__((address_space(1))) const void gvoid_t;

// ---------------- block reduction helper (blockDim == 256) ----------------
template<bool MAXOP>
__device__ __forceinline__ float blockReduce(float v, float* s){
  #pragma unroll
  for (int o = 32; o; o >>= 1){
    float t = __shfl_xor(v, o);
    v = MAXOP ? fmaxf(v, t) : (v + t);
  }
  int lane = threadIdx.x & 63, w = threadIdx.x >> 6;
  if (lane == 0) s[w] = v;
  __syncthreads();
  float r = s[0];
  #pragma unroll
  for (int i = 1; i < 4; i++) r = MAXOP ? fmaxf(r, s[i]) : (r + s[i]);
  __syncthreads();
  return r;
}

// ---------------- weight conversion fp32 -> bf16 ----------------
struct W18 { const float* p[18]; };

__global__ __launch_bounds__(256) void conv_weights(W18 w, bf16_t* __restrict__ out){
  int m = blockIdx.y;
  int i = blockIdx.x * 256 + threadIdx.x;   // grid.x*256 == HH exactly
  out[(size_t)m * HH + i] = (bf16_t)w.p[m][i];
}

__global__ __launch_bounds__(256) void f2b_kernel(const float* __restrict__ in, bf16_t* __restrict__ out, long n){
  long i = (long)blockIdx.x * blockDim.x + threadIdx.x;
  long stride = (long)gridDim.x * blockDim.x;
  for (; i < n; i += stride) out[i] = (bf16_t)in[i];
}

// ---------------- LayerNorm: fp32 out + bf16 out ----------------
__global__ __launch_bounds__(256) void ln_kernel(const float* __restrict__ x,
                                                 const float* __restrict__ w,
                                                 const float* __restrict__ b,
                                                 float* __restrict__ outf,
                                                 bf16_t* __restrict__ outb){
  __shared__ float red[4];
  int row = blockIdx.x, t = threadIdx.x;
  size_t base = (size_t)row * H_;
  float v[3]; float sum = 0.f, sq = 0.f;
  #pragma unroll
  for (int i = 0; i < 3; i++){
    v[i] = x[base + t + i*256];
    sum += v[i]; sq += v[i]*v[i];
  }
  sum = blockReduce<false>(sum, red);
  sq  = blockReduce<false>(sq,  red);
  float mu  = sum * (1.f/H_);
  float var = sq  * (1.f/H_) - mu*mu;
  float rstd = rsqrtf(var + 1e-5f);
  #pragma unroll
  for (int i = 0; i < 3; i++){
    int j = t + i*256;
    float y = (v[i]-mu)*rstd*w[j] + b[j];
    outf[base+j] = y;
    outb[base+j] = (bf16_t)y;
  }
}

// ---------------- generic C = A * B^T bf16 MFMA GEMM ----------------
// A [M,K] bf16 (lda=K), B [N,K] bf16 (ldb=K), C [M,N] f32 (ldc=N)
// z-batch via strides; scale per z; bias applied only at z==0; causal tile-skip.
__global__ __launch_bounds__(256) void gemm_bt(const bf16_t* __restrict__ A,
                                               const bf16_t* __restrict__ Bm,
                                               float* __restrict__ C,
                                               int M, int N, int K,
                                               long sA, long sB, long sC,
                                               float scale0, float scale1, float scale2,
                                               const float* __restrict__ bias0, int causal){
  int z = blockIdx.z;
  A  += (size_t)z * sA;
  Bm += (size_t)z * sB;
  C  += (size_t)z * sC;
  float scale = (z==0) ? scale0 : (z==1) ? scale1 : scale2;
  const float* bias = (z==0) ? bias0 : nullptr;

  int bm = blockIdx.y, bn = blockIdx.x;
  int row0 = bm * 128, col0 = bn * 128;
  if (causal && col0 > row0) return;   // fully-masked tile

  __shared__ bf16_t As[2][128*32];
  __shared__ bf16_t Bs[2][128*32];

  int tid  = threadIdx.x;
  int lane = tid & 63, wave = tid >> 6;
  int wm = wave >> 1, wn = wave & 1;      // 2x2 wave grid, 64x64 per wave
  int lr = lane & 15, kg = lane >> 4;

  f32x4 acc[4][4] = {};
  int NT = K >> 5;  // BK = 32

  auto stage = [&](int buf, int kt){
    int kk = kt * 32;
    #pragma unroll
    for (int i = 0; i < 2; i++){
      int c  = tid + i*256;            // 16B chunk index 0..511
      int r  = c >> 2;                 // tile row 0..127
      int c8 = (c & 3) * 8;            // bf16 col offset within BK
      __builtin_amdgcn_global_load_lds((gvoid_t*)(A  + (size_t)(row0 + r)*K + kk + c8),
                                       (lds_void_t*)(&As[buf][c*8]), 16, 0, 0);
      __builtin_amdgcn_global_load_lds((gvoid_t*)(Bm + (size_t)(col0 + r)*K + kk + c8),
                                       (lds_void_t*)(&Bs[buf][c*8]), 16, 0, 0);
    }
  };

  stage(0, 0);
  __syncthreads();
  int buf = 0;
  for (int kt = 0; kt < NT; ++kt){
    if (kt + 1 < NT) stage(buf ^ 1, kt + 1);
    bf16x8 af[4], bfr[4];
    #pragma unroll
    for (int m = 0; m < 4; m++)
      af[m] = *reinterpret_cast<const bf16x8*>(&As[buf][(wm*64 + m*16 + lr)*32 + kg*8]);
    #pragma unroll
    for (int n = 0; n < 4; n++)
      bfr[n] = *reinterpret_cast<const bf16x8*>(&Bs[buf][(wn*64 + n*16 + lr)*32 + kg*8]);
    #pragma unroll
    for (int m = 0; m < 4; m++)
      #pragma unroll
      for (int n = 0; n < 4; n++)
        acc[m][n] = __builtin_amdgcn_mfma_f32_16x16x32_bf16(af[m], bfr[n], acc[m][n], 0, 0, 0);
    __syncthreads();   // drains vmcnt: next buf fully staged; old buf free to overwrite
    buf ^= 1;
  }

  // epilogue: C/D layout col=lane&15, row=(lane>>4)*4+reg
  #pragma unroll
  for (int m = 0; m < 4; m++){
    int rb = row0 + wm*64 + m*16 + kg*4;
    #pragma unroll
    for (int n = 0; n < 4; n++){
      int cc = col0 + wn*64 + n*16 + lr;
      float bv = bias ? bias[cc] : 0.f;
      #pragma unroll
      for (int r = 0; r < 4; r++)
        C[(size_t)(rb + r)*N + cc] = acc[m][n][r]*scale + bv;
    }
  }
}

// ---------------- gate branch (one row of 768 per block) ----------------
// mode 0: rope -> outb (q/k) ; mode 1: plain bf16 -> outb (v)
// mode 2: + resid -> outf     ; mode 3: relu -> outf + outb
__global__ __launch_bounds__(256) void gate_kernel(const float* __restrict__ inp,
                                                   const float* __restrict__ c3,
                                                   const float* __restrict__ cosT,
                                                   const float* __restrict__ sinT,
                                                   const float* __restrict__ resid,
                                                   float* __restrict__ outf,
                                                   bf16_t* __restrict__ outb,
                                                   int mode){
  __shared__ float red[4];
  __shared__ float sh[H_];
  int row = blockIdx.x, t = threadIdx.x;
  size_t base = (size_t)row * H_;

  float iv[3], cv[3], mv[3], gv[3];
  float gmax = 0.f;
  #pragma unroll
  for (int i = 0; i < 3; i++){
    int j = t + i*256;
    iv[i] = inp[base + j];
    cv[i] = c3[base + j];
    mv[i] = c3[MN   + base + j];
    gv[i] = c3[2*MN + base + j];
    gmax  = fmaxf(gmax, fabsf(gv[i]));
  }
  gmax = blockReduce<true>(gmax, red);
  float rg = 1.f / (gmax + 1e-9f);

  float rt[3]; float rmax = 0.f;
  #pragma unroll
  for (int i = 0; i < 3; i++){
    float masg = fmaxf(gv[i]*rg, 0.f);     // relu(gate / (max|gate|+eps))
    rt[i] = mv[i] - masg;                  // routing logits (gain = 1)
    rmax  = fmaxf(rmax, fabsf(rt[i]));
  }
  rmax = blockReduce<true>(rmax, red);
  float rr = 1.f / (rmax + 1e-9f);

  if (mode == 0){
    #pragma unroll
    for (int i = 0; i < 3; i++){
      int j = t + i*256;
      sh[j] = (iv[i] + cv[i]) * fmaxf(rt[i]*rr, 0.f);
    }
    __syncthreads();
    int s = row & (S_ - 1);
    #pragma unroll
    for (int i = 0; i < 3; i++){
      int j = t + i*256;
      float partner = (j < H_/2) ? -sh[j + H_/2] : sh[j - H_/2];
      float o = sh[j]*cosT[(size_t)s*H_ + j] + partner*sinT[(size_t)s*H_ + j];
      outb[base + j] = (bf16_t)o;
    }
  } else {
    #pragma unroll
    for (int i = 0; i < 3; i++){
      int j = t + i*256;
      float val = (iv[i] + cv[i]) * fmaxf(rt[i]*rr, 0.f);
      if (mode == 1)      outb[base + j] = (bf16_t)val;
      else if (mode == 2) outf[base + j] = val + resid[base + j];
      else { val = fmaxf(val, 0.f); outf[base + j] = val; outb[base + j] = (bf16_t)val; }
    }
  }
}

// ---------------- causal softmax: fp32 scores -> bf16 P ----------------
__global__ __launch_bounds__(256) void softmax_causal(const float* __restrict__ sc,
                                                      bf16_t* __restrict__ P){
  __shared__ float red[4];
  int r = blockIdx.x, t = threadIdx.x;
  const float* srow = sc + (size_t)r * S_;
  bf16_t* prow = P + (size_t)r * S_;
  int n = r + 1;
  float m = -1e30f;
  for (int j = t; j < n; j += 256) m = fmaxf(m, srow[j]);
  m = blockReduce<true>(m, red);
  float sum = 0.f;
  for (int j = t; j < n; j += 256) sum += __expf(srow[j] - m);
  sum = blockReduce<false>(sum, red);
  float inv = 1.f / sum;
  for (int j = t; j < S_; j += 256)
    prow[j] = (j < n) ? (bf16_t)(__expf(srow[j] - m)*inv) : (bf16_t)0.f;
}

// ---------------- 32x32 tiled transpose [B,S,H] -> [B,H,S] ----------------
__global__ __launch_bounds__(256) void transpose_bf(const bf16_t* __restrict__ in,
                                                    bf16_t* __restrict__ out){
  __shared__ bf16_t tile[32][33];
  int bz = blockIdx.z;
  const bf16_t* I = in  + (size_t)bz * S_ * H_;
  bf16_t*       O = out + (size_t)bz * (size_t)H_ * S_;
  int s0 = blockIdx.x*32, h0 = blockIdx.y*32;
  int tx = threadIdx.x, ty = threadIdx.y;   // 32 x 8
  #pragma unroll
  for (int k = 0; k < 4; k++)
    tile[ty + 8*k][tx] = I[(size_t)(s0 + ty + 8*k)*H_ + h0 + tx];
  __syncthreads();
  #pragma unroll
  for (int k = 0; k < 4; k++)
    O[(size_t)(h0 + ty + 8*k)*S_ + s0 + tx] = tile[tx][ty + 8*k];
}

// ---------------- launch ----------------
extern "C" void kernel_launch(void* const* d_in, const int* in_sizes, int n_in,
                              void* d_out, int out_size, void* d_ws, size_t ws_size,
                              hipStream_t stream){
  const float* x    = (const float*)d_in[0];
  const float* cosT = (const float*)d_in[1];
  const float* sinT = (const float*)d_in[2];
  const float* ln1w = (const float*)d_in[3];
  const float* ln1b = (const float*)d_in[4];
  const float* ln2w = (const float*)d_in[5];
  const float* ln2b = (const float*)d_in[6];

  W18 wp; const float* bias[6];
  for (int i = 0; i < 6; i++){
    const float* proto = (const float*)d_in[7 + 4*i + 0];
    const float* gatep = (const float*)d_in[7 + 4*i + 1];
    const float* muw   = (const float*)d_in[7 + 4*i + 2];
    bias[i]            = (const float*)d_in[7 + 4*i + 3];
    wp.p[i*3 + 0] = muw;    // z=0: comp
    wp.p[i*3 + 1] = proto;  // z=1: match
    wp.p[i*3 + 2] = gatep;  // z=2: gate
  }

  // workspace layout (~261 MB total)
  char* w = (char*)d_ws;
  auto alloc = [&](size_t bytes){ void* r = (void*)w; w += (bytes + 255) & ~(size_t)255; return r; };
  bf16_t* w_bf  = (bf16_t*)alloc((size_t)18 * HH * 2);
  float*  t_ln  = (float*) alloc(MN * 4);
  bf16_t* a_bf  = (bf16_t*)alloc(MN * 2);
  float*  c3    = (float*) alloc(3 * MN * 4);
  bf16_t* q_bf  = (bf16_t*)alloc(MN * 2);
  bf16_t* k_bf  = (bf16_t*)alloc(MN * 2);
  bf16_t* v_bf  = (bf16_t*)alloc(MN * 2);
  bf16_t* vt    = (bf16_t*)alloc(MN * 2);
  float*  scores= (float*) alloc((size_t)S_ * S_ * 4);
  bf16_t* p_bf  = (bf16_t*)alloc((size_t)S_ * S_ * 2);
  float*  attn  = (float*) alloc(MN * 4);   // also reused as h_act fp32
  float*  x1    = (float*) alloc(MN * 4);
  (void)ws_size;

  const float rs = 1.0f / sqrtf((float)H_);

  conv_weights<<<dim3(HH/256, 18), 256, 0, stream>>>(wp, w_bf);
  ln_kernel<<<M_, 256, 0, stream>>>(x, ln1w, ln1b, t_ln, a_bf);

  bf16_t* qkv[3] = {q_bf, k_bf, v_bf};
  for (int s = 0; s < 3; s++){
    gemm_bt<<<dim3(H_/128, M_/128, 3), 256, 0, stream>>>(
        a_bf, w_bf + (size_t)s*3*HH, c3, M_, H_, H_,
        0, (long)HH, (long)MN, 1.f, rs, 1.f, bias[s], 0);
    gate_kernel<<<M_, 256, 0, stream>>>(t_ln, c3, cosT, sinT, nullptr, nullptr, qkv[s], (s < 2) ? 0 : 1);
  }

  transpose_bf<<<dim3(S_/32, H_/32, B_), dim3(32, 8), 0, stream>>>(v_bf, vt);

  for (int b = 0; b < B_; b++){
    gemm_bt<<<dim3(S_/128, S_/128, 1), 256, 0, stream>>>(
        q_bf + (size_t)b*S_*H_, k_bf + (size_t)b*S_*H_, scores,
        S_, S_, H_, 0, 0, 0, rs, rs, rs, nullptr, 1);
    softmax_causal<<<S_, 256, 0, stream>>>(scores, p_bf);
    gemm_bt<<<dim3(H_/128, S_/128, 1), 256, 0, stream>>>(
        p_bf, vt + (size_t)b*(size_t)H_*S_, attn + (size_t)b*S_*H_,
        S_, H_, S_, 0, 0, 0, 1.f, 1.f, 1.f, nullptr, 0);
  }

  f2b_kernel<<<2048, 256, 0, stream>>>(attn, a_bf, (long)MN);

  // o-SPL + gate(+residual x) -> x1
  gemm_bt<<<dim3(H_/128, M_/128, 3), 256, 0, stream>>>(
      a_bf, w_bf + (size_t)9*HH, c3, M_, H_, H_, 0, (long)HH, (long)MN, 1.f, rs, 1.f, bias[3], 0);
  gate_kernel<<<M_, 256, 0, stream>>>(attn, c3, nullptr, nullptr, x, x1, nullptr, 2);

  // LN2
  ln_kernel<<<M_, 256, 0, stream>>>(x1, ln2w, ln2b, t_ln, a_bf);

  // f1-SPL + gate + relu -> h (attn buffer reused) + a_bf
  gemm_bt<<<dim3(H_/128, M_/128, 3), 256, 0, stream>>>(
      a_bf, w_bf + (size_t)12*HH, c3, M_, H_, H_, 0, (long)HH, (long)MN, 1.f, rs, 1.f, bias[4], 0);
  gate_kernel<<<M_, 256, 0, stream>>>(t_ln, c3, nullptr, nullptr, nullptr, attn, a_bf, 3);

  // f2-SPL + gate(+residual x1) -> d_out
  gemm_bt<<<dim3(H_/128, M_/128, 3), 256, 0, stream>>>(
      a_bf, w_bf + (size_t)15*HH, c3, M_, H_, H_, 0, (long)HH, (long)MN, 1.f, rs, 1.f, bias[5], 0);
  gate_kernel<<<M_, 256, 0, stream>>>(attn, c3, nullptr, nullptr, x1, (float*)d_out, nullptr, 2);
}

// Round 2
// 525.591 us; speedup vs baseline: 1.5886x; 1.5886x over previous
//
#include <hip/hip_runtime.h>
#include <hip/hip_bf16.h>
#include <math.h>

#define B_ 4
#define S_ 2048
#define H_ 768
#define M_ (B_*S_)                 // 8192 rows
#define MN ((size_t)M_*(size_t)H_) // 6291456
#define HH (H_*H_)                 // 589824
#define SS ((size_t)S_*(size_t)S_)
#define SH ((size_t)S_*(size_t)H_)

typedef __bf16 bf16_t;
typedef __bf16 bf16x8 __attribute__((ext_vector_type(8)));
typedef float  f32x4  __attribute__((ext_vector_type(4)));

typedef __attribute__((address_space(3))) void       lds_void_t;
typedef __attribute__((address_space(1))) const void gvoid_t;

// ---------------- block reduction helper (blockDim == 256) ----------------
template<bool MAXOP>
__device__ __forceinline__ float blockReduce(float v, float* s){
  #pragma unroll
  for (int o = 32; o; o >>= 1){
    float t = __shfl_xor(v, o);
    v = MAXOP ? fmaxf(v, t) : (v + t);
  }
  int lane = threadIdx.x & 63, w = threadIdx.x >> 6;
  if (lane == 0) s[w] = v;
  __syncthreads();
  float r = s[0];
  #pragma unroll
  for (int i = 1; i < 4; i++) r = MAXOP ? fmaxf(r, s[i]) : (r + s[i]);
  __syncthreads();
  return r;
}

// ---------------- weight conversion fp32 -> bf16 ----------------
struct W18 { const float* p[18]; };

__global__ __launch_bounds__(256) void conv_weights(W18 w, bf16_t* __restrict__ out){
  int m = blockIdx.y;
  int i = blockIdx.x * 256 + threadIdx.x;   // grid.x*256 == HH exactly
  out[(size_t)m * HH + i] = (bf16_t)w.p[m][i];
}

// ---------------- LayerNorm: bf16 out ----------------
__global__ __launch_bounds__(256) void ln_kernel(const float* __restrict__ x,
                                                 const float* __restrict__ w,
                                                 const float* __restrict__ b,
                                                 bf16_t* __restrict__ outb){
  __shared__ float red[4];
  int row = blockIdx.x, t = threadIdx.x;
  size_t base = (size_t)row * H_;
  float v[3]; float sum = 0.f, sq = 0.f;
  #pragma unroll
  for (int i = 0; i < 3; i++){
    v[i] = x[base + t + i*256];
    sum += v[i]; sq += v[i]*v[i];
  }
  sum = blockReduce<false>(sum, red);
  sq  = blockReduce<false>(sq,  red);
  float mu  = sum * (1.f/H_);
  float var = sq  * (1.f/H_) - mu*mu;
  float rstd = rsqrtf(var + 1e-5f);
  #pragma unroll
  for (int i = 0; i < 3; i++){
    int j = t + i*256;
    outb[base+j] = (bf16_t)((v[i]-mu)*rstd*w[j] + b[j]);
  }
}

// ---------------- generic C = A * B^T bf16 MFMA GEMM, bf16 C out ----------------
// A [M,K] bf16, B [N,K] bf16, C [M,N] bf16. z-batch via strides; scale per z;
// bias applied only at z==0; cmode: 0 none, 1 causal tile-skip, 2 causal K-limit.
__global__ __launch_bounds__(256) void gemm_bt(const bf16_t* __restrict__ A,
                                               const bf16_t* __restrict__ Bm,
                                               bf16_t* __restrict__ C,
                                               int M, int N, int K,
                                               long sA, long sB, long sC,
                                               float scale0, float scale1, float scale2,
                                               const float* __restrict__ bias0, int cmode){
  // bijective XCD swizzle over flat id (nwg % 8 == 0 for all our grids)
  int gx = gridDim.x, gy = gridDim.y;
  int nwg = gx * gy * gridDim.z;
  int id  = (blockIdx.z * gy + blockIdx.y) * gx + blockIdx.x;
  int sid = (id & 7) * (nwg >> 3) + (id >> 3);
  int bx  = sid % gx;
  int by  = (sid / gx) % gy;
  int z   = sid / (gx * gy);

  A  += (size_t)z * sA;
  Bm += (size_t)z * sB;
  C  += (size_t)z * sC;
  float scale = (z==0) ? scale0 : (z==1) ? scale1 : scale2;
  const float* bias = (z==0) ? bias0 : nullptr;

  int row0 = by * 128, col0 = bx * 128;
  if (cmode == 1 && col0 > row0) return;   // fully-masked tile

  __shared__ bf16_t As[2][128*32];
  __shared__ bf16_t Bs[2][128*32];

  int tid  = threadIdx.x;
  int lane = tid & 63;
  int wave = tid >> 6;
  int wm = wave >> 1, wn = wave & 1;      // 2x2 wave grid, 64x64 per wave
  int lr = lane & 15, kg = lane >> 4;

  f32x4 acc[4][4] = {};
  int NT = K >> 5;  // BK = 32
  if (cmode == 2) { int lim = (row0 + 128) >> 5; NT = NT < lim ? NT : lim; }

  auto stage = [&](int buf, int kt){
    int kk = kt * 32;
    #pragma unroll
    for (int i = 0; i < 2; i++){
      int c  = tid + i*256;            // 16B chunk index 0..511
      int r  = c >> 2;                 // tile row 0..127
      int c8 = (c & 3) * 8;            // bf16 col offset within BK
      __builtin_amdgcn_global_load_lds((gvoid_t*)(A  + (size_t)(row0 + r)*K + kk + c8),
                                       (lds_void_t*)(&As[buf][c*8]), 16, 0, 0);
      __builtin_amdgcn_global_load_lds((gvoid_t*)(Bm + (size_t)(col0 + r)*K + kk + c8),
                                       (lds_void_t*)(&Bs[buf][c*8]), 16, 0, 0);
    }
  };

  stage(0, 0);
  __syncthreads();
  int buf = 0;
  for (int kt = 0; kt < NT; ++kt){
    if (kt + 1 < NT) stage(buf ^ 1, kt + 1);
    bf16x8 af[4], bfr[4];
    #pragma unroll
    for (int m = 0; m < 4; m++)
      af[m] = *reinterpret_cast<const bf16x8*>(&As[buf][(wm*64 + m*16 + lr)*32 + kg*8]);
    #pragma unroll
    for (int n = 0; n < 4; n++)
      bfr[n] = *reinterpret_cast<const bf16x8*>(&Bs[buf][(wn*64 + n*16 + lr)*32 + kg*8]);
    #pragma unroll
    for (int m = 0; m < 4; m++)
      #pragma unroll
      for (int n = 0; n < 4; n++)
        acc[m][n] = __builtin_amdgcn_mfma_f32_16x16x32_bf16(af[m], bfr[n], acc[m][n], 0, 0, 0);
    __syncthreads();
    buf ^= 1;
  }

  // epilogue: C/D layout col=lane&15, row=(lane>>4)*4+reg
  #pragma unroll
  for (int m = 0; m < 4; m++){
    int rb = row0 + wm*64 + m*16 + kg*4;
    #pragma unroll
    for (int n = 0; n < 4; n++){
      int cc = col0 + wn*64 + n*16 + lr;
      float bv = bias ? bias[cc] : 0.f;
      #pragma unroll
      for (int r = 0; r < 4; r++)
        C[(size_t)(rb + r)*N + cc] = (bf16_t)(acc[m][n][r]*scale + bv);
    }
  }
}

// ---------------- gate branch (one row of 768 per block) ----------------
// mode 0: rope -> outb (q/k) ; mode 1: plain -> outb (v)
// mode 2: + resid(f32) -> outf ; mode 3: relu -> outb
__global__ __launch_bounds__(256) void gate_kernel(const bf16_t* __restrict__ inp,
                                                   const bf16_t* __restrict__ c3,
                                                   const float* __restrict__ cosT,
                                                   const float* __restrict__ sinT,
                                                   const float* __restrict__ resid,
                                                   float* __restrict__ outf,
                                                   bf16_t* __restrict__ outb,
                                                   int mode){
  __shared__ float red[4];
  __shared__ float sh[H_];
  int row = blockIdx.x, t = threadIdx.x;
  size_t base = (size_t)row * H_;

  float iv[3], cv[3], mv[3], gv[3];
  float gmax = 0.f;
  #pragma unroll
  for (int i = 0; i < 3; i++){
    int j = t + i*256;
    iv[i] = (float)inp[base + j];
    cv[i] = (float)c3[base + j];
    mv[i] = (float)c3[MN   + base + j];
    gv[i] = (float)c3[2*MN + base + j];
    gmax  = fmaxf(gmax, fabsf(gv[i]));
  }
  gmax = blockReduce<true>(gmax, red);
  float rg = 1.f / (gmax + 1e-9f);

  float rt[3]; float rmax = 0.f;
  #pragma unroll
  for (int i = 0; i < 3; i++){
    float masg = fmaxf(gv[i]*rg, 0.f);     // relu(gate / (max|gate|+eps))
    rt[i] = mv[i] - masg;                  // routing logits (gain = 1)
    rmax  = fmaxf(rmax, fabsf(rt[i]));
  }
  rmax = blockReduce<true>(rmax, red);
  float rr = 1.f / (rmax + 1e-9f);

  if (mode == 0){
    #pragma unroll
    for (int i = 0; i < 3; i++){
      int j = t + i*256;
      sh[j] = (iv[i] + cv[i]) * fmaxf(rt[i]*rr, 0.f);
    }
    __syncthreads();
    int s = row & (S_ - 1);
    #pragma unroll
    for (int i = 0; i < 3; i++){
      int j = t + i*256;
      float partner = (j < H_/2) ? -sh[j + H_/2] : sh[j - H_/2];
      float o = sh[j]*cosT[(size_t)s*H_ + j] + partner*sinT[(size_t)s*H_ + j];
      outb[base + j] = (bf16_t)o;
    }
  } else {
    #pragma unroll
    for (int i = 0; i < 3; i++){
      int j = t + i*256;
      float val = (iv[i] + cv[i]) * fmaxf(rt[i]*rr, 0.f);
      if (mode == 1)      outb[base + j] = (bf16_t)val;
      else if (mode == 2) outf[base + j] = val + resid[base + j];
      else                outb[base + j] = (bf16_t)fmaxf(val, 0.f);
    }
  }
}

// ---------------- causal softmax: bf16 scores -> bf16 P, batched over b ----------------
__global__ __launch_bounds__(256) void softmax_causal(const bf16_t* __restrict__ sc,
                                                      bf16_t* __restrict__ P){
  __shared__ float red[4];
  int r = blockIdx.x, b = blockIdx.y, t = threadIdx.x;
  const bf16_t* srow = sc + (size_t)b*SS + (size_t)r * S_;
  bf16_t* prow = P + (size_t)b*SS + (size_t)r * S_;
  int n = r + 1;
  int fill = ((r >> 7) + 1) << 7;          // PV reads k < row0+128; zero up to there
  float m = -1e30f;
  for (int j = t; j < n; j += 256) m = fmaxf(m, (float)srow[j]);
  m = blockReduce<true>(m, red);
  float sum = 0.f;
  for (int j = t; j < n; j += 256) sum += __expf((float)srow[j] - m);
  sum = blockReduce<false>(sum, red);
  float inv = 1.f / sum;
  for (int j = t; j < fill; j += 256)
    prow[j] = (j < n) ? (bf16_t)(__expf((float)srow[j] - m)*inv) : (bf16_t)0.f;
}

// ---------------- 32x32 tiled transpose [B,S,H] -> [B,H,S] ----------------
__global__ __launch_bounds__(256) void transpose_bf(const bf16_t* __restrict__ in,
                                                    bf16_t* __restrict__ out){
  __shared__ bf16_t tile[32][33];
  int bz = blockIdx.z;
  const bf16_t* I = in  + (size_t)bz * SH;
  bf16_t*       O = out + (size_t)bz * SH;
  int s0 = blockIdx.x*32, h0 = blockIdx.y*32;
  int tx = threadIdx.x, ty = threadIdx.y;   // 32 x 8
  #pragma unroll
  for (int k = 0; k < 4; k++)
    tile[ty + 8*k][tx] = I[(size_t)(s0 + ty + 8*k)*H_ + h0 + tx];
  __syncthreads();
  #pragma unroll
  for (int k = 0; k < 4; k++)
    O[(size_t)(h0 + ty + 8*k)*S_ + s0 + tx] = tile[tx][ty + 8*k];
}

// ---------------- launch ----------------
extern "C" void kernel_launch(void* const* d_in, const int* in_sizes, int n_in,
                              void* d_out, int out_size, void* d_ws, size_t ws_size,
                              hipStream_t stream){
  const float* x    = (const float*)d_in[0];
  const float* cosT = (const float*)d_in[1];
  const float* sinT = (const float*)d_in[2];
  const float* ln1w = (const float*)d_in[3];
  const float* ln1b = (const float*)d_in[4];
  const float* ln2w = (const float*)d_in[5];
  const float* ln2b = (const float*)d_in[6];

  W18 wp; const float* bias[6];
  for (int i = 0; i < 6; i++){
    const float* proto = (const float*)d_in[7 + 4*i + 0];
    const float* gatep = (const float*)d_in[7 + 4*i + 1];
    const float* muw   = (const float*)d_in[7 + 4*i + 2];
    bias[i]            = (const float*)d_in[7 + 4*i + 3];
    wp.p[i*3 + 0] = muw;    // z=0: comp
    wp.p[i*3 + 1] = proto;  // z=1: match
    wp.p[i*3 + 2] = gatep;  // z=2: gate
  }

  // workspace layout (~239 MB total)
  char* w = (char*)d_ws;
  auto alloc = [&](size_t bytes){ void* r = (void*)w; w += (bytes + 255) & ~(size_t)255; return r; };
  bf16_t* w_bf   = (bf16_t*)alloc((size_t)18 * HH * 2);
  bf16_t* a_bf   = (bf16_t*)alloc(MN * 2);        // current activation (LN out etc.)
  bf16_t* h_bf   = (bf16_t*)alloc(MN * 2);        // relu hidden
  bf16_t* c3b    = (bf16_t*)alloc(3 * MN * 2);    // comp/match/gate logits
  bf16_t* q_bf   = (bf16_t*)alloc(MN * 2);
  bf16_t* k_bf   = (bf16_t*)alloc(MN * 2);
  bf16_t* v_bf   = (bf16_t*)alloc(MN * 2);
  bf16_t* vt     = (bf16_t*)alloc(MN * 2);
  bf16_t* sc_bf  = (bf16_t*)alloc(B_ * SS * 2);   // scores, all batches
  bf16_t* p_bf   = (bf16_t*)alloc(B_ * SS * 2);
  bf16_t* attn_b = (bf16_t*)alloc(MN * 2);
  float*  x1     = (float*) alloc(MN * 4);
  (void)ws_size;

  const float rs = 1.0f / sqrtf((float)H_);

  conv_weights<<<dim3(HH/256, 18), 256, 0, stream>>>(wp, w_bf);
  ln_kernel<<<M_, 256, 0, stream>>>(x, ln1w, ln1b, a_bf);

  bf16_t* qkv[3] = {q_bf, k_bf, v_bf};
  for (int s = 0; s < 3; s++){
    gemm_bt<<<dim3(H_/128, M_/128, 3), 256, 0, stream>>>(
        a_bf, w_bf + (size_t)s*3*HH, c3b, M_, H_, H_,
        0, (long)HH, (long)MN, 1.f, rs, 1.f, bias[s], 0);
    gate_kernel<<<M_, 256, 0, stream>>>(a_bf, c3b, cosT, sinT, nullptr, nullptr, qkv[s], (s < 2) ? 0 : 1);
  }

  transpose_bf<<<dim3(S_/32, H_/32, B_), dim3(32, 8), 0, stream>>>(v_bf, vt);

  // QK^T, all batches: scores[b] = q[b] @ k[b]^T * rs   (causal tile-skip)
  gemm_bt<<<dim3(S_/128, S_/128, B_), 256, 0, stream>>>(
      q_bf, k_bf, sc_bf, S_, S_, H_,
      (long)SH, (long)SH, (long)SS, rs, rs, rs, nullptr, 1);

  softmax_causal<<<dim3(S_, B_), 256, 0, stream>>>(sc_bf, p_bf);

  // PV, all batches: attn[b] = P[b] @ vt[b]^T  (K limited causally)
  gemm_bt<<<dim3(H_/128, S_/128, B_), 256, 0, stream>>>(
      p_bf, vt, attn_b, S_, H_, S_,
      (long)SS, (long)SH, (long)SH, 1.f, 1.f, 1.f, nullptr, 2);

  // o-SPL + gate(+residual x) -> x1
  gemm_bt<<<dim3(H_/128, M_/128, 3), 256, 0, stream>>>(
      attn_b, w_bf + (size_t)9*HH, c3b, M_, H_, H_, 0, (long)HH, (long)MN, 1.f, rs, 1.f, bias[3], 0);
  gate_kernel<<<M_, 256, 0, stream>>>(attn_b, c3b, nullptr, nullptr, x, x1, nullptr, 2);

  // LN2
  ln_kernel<<<M_, 256, 0, stream>>>(x1, ln2w, ln2b, a_bf);

  // f1-SPL + gate + relu -> h_bf
  gemm_bt<<<dim3(H_/128, M_/128, 3), 256, 0, stream>>>(
      a_bf, w_bf + (size_t)12*HH, c3b, M_, H_, H_, 0, (long)HH, (long)MN, 1.f, rs, 1.f, bias[4], 0);
  gate_kernel<<<M_, 256, 0, stream>>>(a_bf, c3b, nullptr, nullptr, nullptr, nullptr, h_bf, 3);

  // f2-SPL + gate(+residual x1) -> d_out
  gemm_bt<<<dim3(H_/128, M_/128, 3), 256, 0, stream>>>(
      h_bf, w_bf + (size_t)15*HH, c3b, M_, H_, H_, 0, (long)HH, (long)MN, 1.f, rs, 1.f, bias[5], 0);
  gate_kernel<<<M_, 256, 0, stream>>>(h_bf, c3b, nullptr, nullptr, x1, (float*)d_out, nullptr, 2);
}